// Round 15
// baseline (872.507 us; speedup 1.0000x reference)
//
#include <hip/hip_runtime.h>
#include <cstdint>
#include <cstddef>

// ---------------- problem geometry ----------------
#define H_DIM   2560
#define DINNER  8192
#define GHEADS  32
#define DGATE   4096
#define DH      128
#define BSZ     2
#define LSEQ    4096
#define MROWS   (BSZ*LSEQ)     // 8192 token rows
#define NWCOMB  8448           // wcomb rows: x 4096 | B 32 | C 32 | pad 192 | z 4096 (=33*256)
#define NCHUNK  64
#define SCHUNK  (LSEQ/NCHUNK)  // 64

typedef __attribute__((ext_vector_type(4))) float    f32x4;
typedef __attribute__((ext_vector_type(8))) _Float16 f16x8;
typedef unsigned short u16;
typedef unsigned int   u32;

static __device__ __forceinline__ u16 f2h(float f) {
  _Float16 h = (_Float16)f;          // v_cvt_f16_f32, RNE
  union { _Float16 h; u16 u; } v; v.h = h; return v.u;
}
static __device__ __forceinline__ float h2f(u16 u) {
  union { u16 u; _Float16 h; } v; v.u = u; return (float)v.h;
}
static __device__ __forceinline__ float silu(float x) {
  return x / (1.0f + expf(-x));
}

// ---------------- merged prep: hs cast | wout cast | wcomb build ----------------
// f32 inputs are read ONCE -> nontemporal loads (don't pollute L3; keep the f16
// OUTPUTS resident instead, since GEMM1/2 re-read them many times).
__global__ __launch_bounds__(256)
void prep_all(const float* __restrict__ hs, const float* __restrict__ Wqkv,
              const float* __restrict__ Wb, const float* __restrict__ Wa,
              const float* __restrict__ Wout, u16* __restrict__ hs_h,
              u16* __restrict__ wout_h, u16* __restrict__ wcomb) {
  const size_t G1 = (size_t)MROWS * H_DIM / 4;
  const size_t G2 = (size_t)DGATE * H_DIM / 4;
  size_t gid = (size_t)blockIdx.x * 256 + threadIdx.x;
  if (gid < G1) {
    f32x4 v = __builtin_nontemporal_load((const f32x4*)hs + gid);
    ((uint2*)hs_h)[gid] = make_uint2((u32)f2h(v[0]) | ((u32)f2h(v[1]) << 16),
                                     (u32)f2h(v[2]) | ((u32)f2h(v[3]) << 16));
  } else if (gid < G1 + G2) {
    size_t i = gid - G1;
    f32x4 v = __builtin_nontemporal_load((const f32x4*)Wout + i);
    ((uint2*)wout_h)[i] = make_uint2((u32)f2h(v[0]) | ((u32)f2h(v[1]) << 16),
                                     (u32)f2h(v[2]) | ((u32)f2h(v[3]) << 16));
  } else {
    size_t i = gid - G1 - G2;          // 0 .. 8448*640-1
    int row = (int)(i / 640);
    int col = (int)(i - (size_t)row * 640);
    const float* s = nullptr;
    if (row < 4096)              s = Wqkv + (size_t)row * H_DIM;
    else if (row < 4128)         s = Wb + (size_t)(row - 4096) * H_DIM;
    else if (row < 4160)         s = Wa + (size_t)(row - 4128) * H_DIM;
    else if (row >= 4352)        s = Wqkv + (size_t)(4096 + row - 4352) * H_DIM;
    u32 p0 = 0, p1 = 0;
    if (s) {
      f32x4 v = __builtin_nontemporal_load((const f32x4*)s + col);
      p0 = (u32)f2h(v[0]) | ((u32)f2h(v[1]) << 16);
      p1 = (u32)f2h(v[2]) | ((u32)f2h(v[3]) << 16);
    }
    ((uint2*)(wcomb + (size_t)row * H_DIM))[col] = make_uint2(p0, p1);
  }
}

// ---------------- GEMM (exact r7/r13 structure; NT epilogue stores) ----------
static __device__ __forceinline__ void gload16(const u16* g, u16* l) {
  __builtin_amdgcn_global_load_lds(
      (const __attribute__((address_space(1))) u32*)g,
      (__attribute__((address_space(3))) u32*)l, 16, 0, 0);
}

#define BAR()    asm volatile("s_barrier" ::: "memory")
#define WAITV3() asm volatile("s_waitcnt vmcnt(3)" ::: "memory")
#define WAITV0() asm volatile("s_waitcnt vmcnt(0)" ::: "memory")

// C[m,n] = sum_k A[m,k]*Bt[n,k], fp16 in. 128M x 256N tile, 512 thr (8 waves
// 2x4, per-wave 64x64, 4x4 16x16x32 frags). Double-buffered LDS with COUNTED
// vmcnt(3); T2 slot-swizzle (conflict-0); T5 setprio; 48 KB LDS -> 3 blocks/CU.
// r14 diagnosis: FETCH = 33 x A exactly -- the kernel's own 136-220 MB output
// streams evict A from L3 (A has the longest reuse distance). Fix: epilogue
// stores are NONTEMPORAL (no-allocate) so L3 retains A+B (85 MB) -> A fetched
// ~once. Values bit-identical (canary 0.0009765625 must hold).
// MODE 0 (fused GEMM1): bx<16 -> f16 Cxh col bx*256; bx==16 -> f32 Cbc[M][64]
// (wn==0 waves only); bx>16 -> f16 Czh col (bx-17)*256.
// MODE 1 (GEMM2): f32 Cf32, ldc 2560, col bx*256.
template<int MODE>
__global__ __launch_bounds__(512)
void gemm_h(const u16* __restrict__ A, const u16* __restrict__ Bt,
            u16* __restrict__ Cxh, float* __restrict__ Cbc, u16* __restrict__ Czh,
            float* __restrict__ Cf32, int K, int nbx, int cpx) {
  __shared__ __align__(16) u16 As0[128 * 32];
  __shared__ __align__(16) u16 As1[128 * 32];
  __shared__ __align__(16) u16 Bs0[256 * 32];
  __shared__ __align__(16) u16 Bs1[256 * 32];
  const int tid  = threadIdx.x;
  const int lane = tid & 63;
  const int wave = tid >> 6;          // 0..7
  const int wm = (wave & 1) * 64;
  const int wn = (wave >> 1) * 64;
  const int bid = blockIdx.x;
  const int lsw = (bid & 7) * cpx + (bid >> 3);
  const int by  = lsw / nbx;
  const int bx  = lsw - by * nbx;
  const size_t bm = (size_t)by * 128;
  const u16* Ab = A + bm * (size_t)K;
  const u16* Bb = Bt + (size_t)bx * 256 * K;

  const int srow = tid >> 2;                                  // 0..127
  const int scol = (((tid & 3) ^ ((srow >> 1) & 3)) << 3);    // element col

  f32x4 acc[4][4];
#pragma unroll
  for (int i = 0; i < 4; i++)
#pragma unroll
    for (int j = 0; j < 4; j++) acc[i][j] = (f32x4){0.f, 0.f, 0.f, 0.f};

#define STAGE(AS, BS, kk)                                                \
  do {                                                                   \
    gload16(Ab + (size_t)srow * K + (kk) + scol, &AS[tid * 8]);          \
    gload16(Bb + (size_t)srow * K + (kk) + scol, &BS[tid * 8]);          \
    gload16(Bb + (size_t)(128 + srow) * K + (kk) + scol, &BS[4096 + tid * 8]); \
  } while (0)

#define COMPUTE(AS, BS)                                                           \
  do {                                                                            \
    const int fr = lane & 15;                                                     \
    const int fo = (((lane >> 4) ^ ((fr >> 1) & 3)) << 3);  /* swizzled k-off */  \
    f16x8 av[4], bv[4];                                                           \
    _Pragma("unroll")                                                             \
    for (int i = 0; i < 4; i++) av[i] = *(const f16x8*)&AS[(wm + i * 16 + fr) * 32 + fo]; \
    _Pragma("unroll")                                                             \
    for (int j = 0; j < 4; j++) bv[j] = *(const f16x8*)&BS[(wn + j * 16 + fr) * 32 + fo]; \
    __builtin_amdgcn_s_setprio(1);                                                \
    _Pragma("unroll")                                                             \
    for (int i = 0; i < 4; i++)                                                   \
      _Pragma("unroll")                                                           \
      for (int j = 0; j < 4; j++)                                                 \
        acc[i][j] = __builtin_amdgcn_mfma_f32_16x16x32_f16(av[i], bv[j], acc[i][j], 0, 0, 0); \
    __builtin_amdgcn_s_setprio(0);                                                \
  } while (0)

  STAGE(As0, Bs0, 0);            // 3 in flight
  STAGE(As1, Bs1, 32);           // 6 in flight
  WAITV3();                      // buf0's 3 landed (own wave)
  BAR();                         // => all waves' buf0 loads landed
  for (int k0 = 0; k0 < K; k0 += 64) {
    COMPUTE(As0, Bs0);
    BAR();                       // all waves done reading buf0
    if (k0 + 64 < K) { STAGE(As0, Bs0, k0 + 64); WAITV3(); }
    else             { WAITV0(); }
    BAR();                       // buf1 ready
    COMPUTE(As1, Bs1);
    BAR();                       // all waves done reading buf1
    if (k0 + 96 < K) { STAGE(As1, Bs1, k0 + 96); WAITV3(); }
    BAR();                       // buf0 (next) ready
  }
#undef STAGE
#undef COMPUTE

  // C/D layout: col = lane&15, row = (lane>>4)*4 + reg   [verified m89/m91]
  const int cr = (lane >> 4) * 4, ccol = lane & 15;
  if (MODE == 0) {
    if (bx < 16) {
      const size_t cb = (size_t)bx * 256;
#pragma unroll
      for (int i2 = 0; i2 < 4; i2++)
#pragma unroll
        for (int j = 0; j < 4; j++)
#pragma unroll
          for (int r = 0; r < 4; r++)
            __builtin_nontemporal_store(f2h(acc[i2][j][r]),
                &Cxh[(bm + wm + i2 * 16 + cr + r) * (size_t)DGATE + cb + wn + j * 16 + ccol]);
    } else if (bx == 16) {
      if (wn == 0) {   // only cols 0..63 are real (B 0..31, C 32..63)
#pragma unroll
        for (int i2 = 0; i2 < 4; i2++)
#pragma unroll
          for (int j = 0; j < 4; j++)
#pragma unroll
            for (int r = 0; r < 4; r++)
              __builtin_nontemporal_store(acc[i2][j][r],
                  &Cbc[(bm + wm + i2 * 16 + cr + r) * (size_t)64 + j * 16 + ccol]);
      }
    } else {
      const size_t cb = (size_t)(bx - 17) * 256;
#pragma unroll
      for (int i2 = 0; i2 < 4; i2++)
#pragma unroll
        for (int j = 0; j < 4; j++)
#pragma unroll
          for (int r = 0; r < 4; r++)
            __builtin_nontemporal_store(f2h(acc[i2][j][r]),
                &Czh[(bm + wm + i2 * 16 + cr + r) * (size_t)DGATE + cb + wn + j * 16 + ccol]);
    }
  } else {
    const size_t cb = (size_t)bx * 256;
#pragma unroll
    for (int i2 = 0; i2 < 4; i2++)
#pragma unroll
      for (int j = 0; j < 4; j++)
#pragma unroll
        for (int r = 0; r < 4; r++)
          __builtin_nontemporal_store(acc[i2][j][r],
              &Cf32[(bm + wm + i2 * 16 + cr + r) * (size_t)H_DIM + cb + wn + j * 16 + ccol]);
  }
}

// ---------------- chunked SSM scan (vectorized: lane owns adjacent chans 2l,2l+1) --
// xh/zh: [M][4096] f16. xbc: [M][64] f32 (B cols 0..31, C cols 32..63).
__global__ __launch_bounds__(64)
void scan_pass1(const u16* __restrict__ xh, const float* __restrict__ xbc,
                const float* __restrict__ conv_w,
                const float* __restrict__ A_log, const float* __restrict__ dt_bias,
                float* __restrict__ E) {
  const int bid = blockIdx.x;
  const int c   = bid & (NCHUNK - 1);
  const int bg  = bid >> 6;
  const int g   = bg & (GHEADS - 1);
  const int b   = bg >> 5;
  const int lane = threadIdx.x;
  const int c0 = g * DH + 2 * lane;    // channels c0, c0+1 (adjacent)

  const f32x4 w0 = ((const f32x4*)conv_w)[c0];
  const f32x4 w1 = ((const f32x4*)conv_w)[c0 + 1];
  const float dt = log1pf(expf(dt_bias[g]));
  const float Ac = -expf(A_log[g]);
  const float dA = expf(dt * Ac);

  const int l0 = c * SCHUNK;
  const u16*   basex = xh  + (size_t)b * LSEQ * DGATE;
  const float* baseb = xbc + (size_t)b * LSEQ * 64;

  float xm3 = 0, xm2 = 0, xm1 = 0, Xm3 = 0, Xm2 = 0, Xm1 = 0;
#pragma unroll
  for (int j = 0; j < 3; j++) {
    int l = l0 - 3 + j;
    float v0 = 0, v1 = 0;
    if (l >= 0) {
      u32 v = *(const u32*)&basex[(size_t)l * DGATE + c0];
      v0 = h2f((u16)v); v1 = h2f((u16)(v >> 16));
    }
    if (j == 0) { xm3 = v0; Xm3 = v1; }
    else if (j == 1) { xm2 = v0; Xm2 = v1; }
    else { xm1 = v0; Xm1 = v1; }
  }
  float h0 = 0.f, h1 = 0.f;
  for (int t = 0; t < SCHUNK; t++) {
    const int l = l0 + t;
    u32 v = *(const u32*)&basex[(size_t)l * DGATE + c0];
    float xc0 = h2f((u16)v), xc1 = h2f((u16)(v >> 16));
    float cx0 = w0[0] * xm3 + w0[1] * xm2 + w0[2] * xm1 + w0[3] * xc0;
    float cx1 = w1[0] * Xm3 + w1[1] * Xm2 + w1[2] * Xm1 + w1[3] * xc1;
    xm3 = xm2; xm2 = xm1; xm1 = xc0;
    Xm3 = Xm2; Xm2 = Xm1; Xm1 = xc1;
    float u = dt * baseb[(size_t)l * 64 + g];
    h0 = dA * h0 + u * silu(cx0);
    h1 = dA * h1 + u * silu(cx1);
  }
  ((float2*)(E + (size_t)bid * DH))[lane] = make_float2(h0, h1);
}

__global__ __launch_bounds__(64)
void scan_pass2(const float* __restrict__ E, float* __restrict__ Hs,
                const float* __restrict__ A_log, const float* __restrict__ dt_bias) {
  const int bg = blockIdx.x;
  const int g = bg & (GHEADS - 1);
  const int lane = threadIdx.x;
  const float dt = log1pf(expf(dt_bias[g]));
  const float Ac = -expf(A_log[g]);
  const float dAS = expf(dt * Ac * (float)SCHUNK);
  float h0 = 0.f, h1 = 0.f;
  for (int c = 0; c < NCHUNK; c++) {
    size_t idx = ((size_t)bg * NCHUNK + c) * DH;
    Hs[idx + lane] = h0; Hs[idx + lane + 64] = h1;
    h0 = dAS * h0 + E[idx + lane];
    h1 = dAS * h1 + E[idx + lane + 64];
  }
}

__global__ __launch_bounds__(64)
void scan_pass3(const u16* __restrict__ xh, const u16* __restrict__ zh,
                const float* __restrict__ xbc, const float* __restrict__ conv_w,
                const float* __restrict__ A_log, const float* __restrict__ dt_bias,
                const float* __restrict__ norm_w, const float* __restrict__ Hs,
                u16* __restrict__ gbuf) {
  const int bid = blockIdx.x;
  const int c   = bid & (NCHUNK - 1);
  const int bg  = bid >> 6;
  const int g   = bg & (GHEADS - 1);
  const int b   = bg >> 5;
  const int lane = threadIdx.x;
  const int c0 = g * DH + 2 * lane;    // channels c0, c0+1 (adjacent)

  const f32x4 wx0 = ((const f32x4*)conv_w)[c0];
  const f32x4 wx1 = ((const f32x4*)conv_w)[c0 + 1];
  const f32x4 wz0 = ((const f32x4*)conv_w)[DGATE + c0];
  const f32x4 wz1 = ((const f32x4*)conv_w)[DGATE + c0 + 1];
  const float nw0 = norm_w[2 * lane], nw1 = norm_w[2 * lane + 1];

  const float dt = log1pf(expf(dt_bias[g]));
  const float Ac = -expf(A_log[g]);
  const float dA = expf(dt * Ac);

  const int l0 = c * SCHUNK;
  const u16*   basex = xh  + (size_t)b * LSEQ * DGATE;
  const u16*   basez = zh  + (size_t)b * LSEQ * DGATE;
  const float* baseb = xbc + (size_t)b * LSEQ * 64;

  float xm3 = 0, xm2 = 0, xm1 = 0, Xm3 = 0, Xm2 = 0, Xm1 = 0;
  float zm3 = 0, zm2 = 0, zm1 = 0, Zm3 = 0, Zm2 = 0, Zm1 = 0;
#pragma unroll
  for (int j = 0; j < 3; j++) {
    int l = l0 - 3 + j;
    float vx0 = 0, vx1 = 0, vz0 = 0, vz1 = 0;
    if (l >= 0) {
      u32 vx = *(const u32*)&basex[(size_t)l * DGATE + c0];
      u32 vz = *(const u32*)&basez[(size_t)l * DGATE + c0];
      vx0 = h2f((u16)vx); vx1 = h2f((u16)(vx >> 16));
      vz0 = h2f((u16)vz); vz1 = h2f((u16)(vz >> 16));
    }
    if (j == 0) { xm3 = vx0; Xm3 = vx1; zm3 = vz0; Zm3 = vz1; }
    else if (j == 1) { xm2 = vx0; Xm2 = vx1; zm2 = vz0; Zm2 = vz1; }
    else { xm1 = vx0; Xm1 = vx1; zm1 = vz0; Zm1 = vz1; }
  }
  float2 hini = ((const float2*)(Hs + (size_t)bid * DH))[lane];
  float h0 = hini.x, h1 = hini.y;
  for (int t = 0; t < SCHUNK; t++) {
    const int l = l0 + t;
    u32 vx = *(const u32*)&basex[(size_t)l * DGATE + c0];
    u32 vz = *(const u32*)&basez[(size_t)l * DGATE + c0];
    float xc0 = h2f((u16)vx), xc1 = h2f((u16)(vx >> 16));
    float zc0 = h2f((u16)vz), zc1 = h2f((u16)(vz >> 16));
    float cx0 = wx0[0] * xm3 + wx0[1] * xm2 + wx0[2] * xm1 + wx0[3] * xc0;
    float cx1 = wx1[0] * Xm3 + wx1[1] * Xm2 + wx1[2] * Xm1 + wx1[3] * xc1;
    float cz0 = wz0[0] * zm3 + wz0[1] * zm2 + wz0[2] * zm1 + wz0[3] * zc0;
    float cz1 = wz1[0] * Zm3 + wz1[1] * Zm2 + wz1[2] * Zm1 + wz1[3] * zc1;
    xm3 = xm2; xm2 = xm1; xm1 = xc0;  Xm3 = Xm2; Xm2 = Xm1; Xm1 = xc1;
    zm3 = zm2; zm2 = zm1; zm1 = zc0;  Zm3 = Zm2; Zm2 = Zm1; Zm1 = zc1;
    float bcl = baseb[(size_t)l * 64 + g];
    float ccl = baseb[(size_t)l * 64 + 32 + g];
    float u = dt * bcl;
    h0 = dA * h0 + u * silu(cx0);
    h1 = dA * h1 + u * silu(cx1);
    float y0 = ccl * h0, y1 = ccl * h1;
    float ss = y0 * y0 + y1 * y1;
    ss += __shfl_xor(ss, 32); ss += __shfl_xor(ss, 16); ss += __shfl_xor(ss, 8);
    ss += __shfl_xor(ss, 4);  ss += __shfl_xor(ss, 2);  ss += __shfl_xor(ss, 1);
    const float sc = rsqrtf(ss * (1.0f / DH) + 1e-6f);
    u32 o = (u32)f2h(y0 * sc * nw0 * silu(cz0)) |
            ((u32)f2h(y1 * sc * nw1 * silu(cz1)) << 16);
    *(u32*)&gbuf[(size_t)(b * LSEQ + l) * DGATE + c0] = o;   // cached: GEMM2 re-reads
  }
}

// ---------------- launch ----------------
extern "C" void kernel_launch(void* const* d_in, const int* in_sizes, int n_in,
                              void* d_out, int out_size, void* d_ws, size_t ws_size,
                              hipStream_t stream) {
  (void)in_sizes; (void)n_in; (void)out_size; (void)ws_size;
  const float* hs    = (const float*)d_in[0];
  const float* Wqkv  = (const float*)d_in[1];
  const float* Wb    = (const float*)d_in[2];
  const float* Wa    = (const float*)d_in[3];
  const float* convw = (const float*)d_in[4];
  const float* Wout  = (const float*)d_in[5];
  const float* normw = (const float*)d_in[6];
  const float* Alog  = (const float*)d_in[7];
  const float* dtb   = (const float*)d_in[8];
  float* out = (float*)d_out;

  // ws layout (~230 MB; <= 313 proven-safe):
  // [xh 67.1 | zh 67.1 | xbc 2.1 | wcomb 43.3 | pad 25 | wout 21.0 | E 2.1 | Hst 2.1]
  char* ws = (char*)d_ws;
  size_t off = 0;
  auto alloc = [&](size_t bytes) { void* p = ws + off; off += (bytes + 255) & ~(size_t)255; return p; };
  u16*   xh     = (u16*)alloc((size_t)MROWS * DGATE * 2);        // 67.1 MB
  u16*   zh     = (u16*)alloc((size_t)MROWS * DGATE * 2);        // 67.1 MB
  float* xbc    = (float*)alloc((size_t)MROWS * 64 * 4);         // 2.1 MB
  u16*   wcomb  = (u16*)alloc((size_t)NWCOMB * H_DIM * 2);       // 43.3 MB
  (void)alloc((size_t)25 << 20);                                 // 25 MB pad (gbuf tail)
  u16*   wout_h = (u16*)alloc((size_t)H_DIM * DGATE * 2);        // 21.0 MB
  float* E      = (float*)alloc((size_t)BSZ * GHEADS * NCHUNK * DH * 4);
  float* Hst    = (float*)alloc((size_t)BSZ * GHEADS * NCHUNK * DH * 4);
  // gbuf (67.1 MB) aliases [wcomb|pad] (68.3 MB): wcomb is dead after GEMM1;
  // pass3 (writer) launches strictly after it. Never touches wout.
  u16*   gbuf   = wcomb;
  // hs_h (fp16, 41.9 MB) lives in d_out (83.9 MB), dead until GEMM2 overwrites it.
  u16*   hs_h   = (u16*)d_out;

  // merged prep: hs cast + wout cast + wcomb build. 13,271,040 granules / 256.
  prep_all<<<51840, 256, 0, stream>>>(hs, Wqkv, Wb, Wa, Wout, hs_h, wout_h, wcomb);

  // Fused GEMM1: [x -> f16 xh] + [B/C -> f32 xbc] + [z -> f16 zh].
  // grid 33 bx * 64 by = 2112, cpx = 264
  gemm_h<0><<<2112, 512, 0, stream>>>(hs_h, wcomb, xh, xbc, zh, nullptr,
                                      H_DIM, 33, 264);

  scan_pass1<<<BSZ * GHEADS * NCHUNK, 64, 0, stream>>>(xh, xbc, convw, Alog, dtb, E);
  scan_pass2<<<BSZ * GHEADS, 64, 0, stream>>>(E, Hst, Alog, dtb);
  scan_pass3<<<BSZ * GHEADS * NCHUNK, 64, 0, stream>>>(xh, zh, xbc, convw, Alog, dtb,
                                                       normw, Hst, gbuf);

  // GEMM2: out = gated @ W_out^T -> f32 [8192, 2560].  grid 10*64 = 640, cpx = 80
  gemm_h<1><<<640, 512, 0, stream>>>(gbuf, wout_h, nullptr, nullptr, nullptr,
                                     out, DGATE, 10, 80);
}

// Round 16
// 785.010 us; speedup vs baseline: 1.1115x; 1.1115x over previous
//
#include <hip/hip_runtime.h>
#include <cstdint>
#include <cstddef>

// ---------------- problem geometry ----------------
#define H_DIM   2560
#define DINNER  8192
#define GHEADS  32
#define DGATE   4096
#define DH      128
#define BSZ     2
#define LSEQ    4096
#define MROWS   (BSZ*LSEQ)     // 8192 token rows
#define NWCOMB  8448           // wcomb rows: x 4096 | B 32 | C 32 | pad 192 | z 4096 (=33*256)
#define NCHUNK  64
#define SCHUNK  (LSEQ/NCHUNK)  // 64

typedef __attribute__((ext_vector_type(4))) float    f32x4;
typedef __attribute__((ext_vector_type(8))) _Float16 f16x8;
typedef unsigned short u16;
typedef unsigned int   u32;

static __device__ __forceinline__ u16 f2h(float f) {
  _Float16 h = (_Float16)f;          // v_cvt_f16_f32, RNE
  union { _Float16 h; u16 u; } v; v.h = h; return v.u;
}
static __device__ __forceinline__ float h2f(u16 u) {
  union { u16 u; _Float16 h; } v; v.u = u; return (float)v.h;
}
static __device__ __forceinline__ float silu(float x) {
  return x / (1.0f + expf(-x));
}

// ---------------- merged prep: hs cast | wout cast | wcomb build (r14 exact) ----
__global__ __launch_bounds__(256)
void prep_all(const float* __restrict__ hs, const float* __restrict__ Wqkv,
              const float* __restrict__ Wb, const float* __restrict__ Wa,
              const float* __restrict__ Wout, u16* __restrict__ hs_h,
              u16* __restrict__ wout_h, u16* __restrict__ wcomb) {
  const size_t G1 = (size_t)MROWS * H_DIM / 4;
  const size_t G2 = (size_t)DGATE * H_DIM / 4;
  size_t gid = (size_t)blockIdx.x * 256 + threadIdx.x;
  if (gid < G1) {
    f32x4 v = ((const f32x4*)hs)[gid];
    ((uint2*)hs_h)[gid] = make_uint2((u32)f2h(v[0]) | ((u32)f2h(v[1]) << 16),
                                     (u32)f2h(v[2]) | ((u32)f2h(v[3]) << 16));
  } else if (gid < G1 + G2) {
    size_t i = gid - G1;
    f32x4 v = ((const f32x4*)Wout)[i];
    ((uint2*)wout_h)[i] = make_uint2((u32)f2h(v[0]) | ((u32)f2h(v[1]) << 16),
                                     (u32)f2h(v[2]) | ((u32)f2h(v[3]) << 16));
  } else {
    size_t i = gid - G1 - G2;          // 0 .. 8448*640-1
    int row = (int)(i / 640);
    int col = (int)(i - (size_t)row * 640);
    const float* s = nullptr;
    if (row < 4096)              s = Wqkv + (size_t)row * H_DIM;
    else if (row < 4128)         s = Wb + (size_t)(row - 4096) * H_DIM;
    else if (row < 4160)         s = Wa + (size_t)(row - 4128) * H_DIM;
    else if (row >= 4352)        s = Wqkv + (size_t)(4096 + row - 4352) * H_DIM;
    u32 p0 = 0, p1 = 0;
    if (s) {
      f32x4 v = ((const f32x4*)s)[col];
      p0 = (u32)f2h(v[0]) | ((u32)f2h(v[1]) << 16);
      p1 = (u32)f2h(v[2]) | ((u32)f2h(v[3]) << 16);
    }
    ((uint2*)(wcomb + (size_t)row * H_DIM))[col] = make_uint2(p0, p1);
  }
}

// ---------------- GEMM (r13/r14 schedule; TWO-LEVEL bx-slow XCD decode) -------
static __device__ __forceinline__ void gload16(const u16* g, u16* l) {
  __builtin_amdgcn_global_load_lds(
      (const __attribute__((address_space(1))) u32*)g,
      (__attribute__((address_space(3))) u32*)l, 16, 0, 0);
}

#define BAR()    asm volatile("s_barrier" ::: "memory")
#define WAITV3() asm volatile("s_waitcnt vmcnt(3)" ::: "memory")
#define WAITV0() asm volatile("s_waitcnt vmcnt(0)" ::: "memory")

// C[m,n] = sum_k A[m,k]*Bt[n,k], fp16 in. 128M x 256N tile, 512 thr (8 waves
// 2x4, per-wave 64x64, 4x4 16x16x32 frags). Double-buffered LDS with COUNTED
// vmcnt(3); T2 slot-swizzle (conflict-0); T5 setprio; 48 KB LDS -> 3 blocks/CU.
// DECODE (r16 change, r11-measured 0.73 GB FETCH): xcd=bid&7 owns by-stripe
// [xcd*8, xcd*8+8); L=bid>>3: by=xcd*8+(L&7) FAST, bx=L>>3 SLOW -> the 1.3 MB
// B-panel is the L2-stationary operand (reused across 8 by) instead of being
// re-swept (43 MB) once per by; halves L2 misses so more staging loads land
// inside the one-phase vmcnt cover. Schedule itself is byte-identical to r14.
// MODE 0 (fused GEMM1): bx<16 -> f16 Cxh col bx*256; bx==16 -> f32 Cbc[M][64]
// (wn==0 waves only); bx>16 -> f16 Czh col (bx-17)*256.
// MODE 1 (GEMM2): f32 Cf32, ldc 2560, col bx*256.
// grid = nbx*64; M = 8192 (64 by-tiles).
template<int MODE>
__global__ __launch_bounds__(512)
void gemm_h(const u16* __restrict__ A, const u16* __restrict__ Bt,
            u16* __restrict__ Cxh, float* __restrict__ Cbc, u16* __restrict__ Czh,
            float* __restrict__ Cf32, int K, int nbx) {
  __shared__ __align__(16) u16 As0[128 * 32];
  __shared__ __align__(16) u16 As1[128 * 32];
  __shared__ __align__(16) u16 Bs0[256 * 32];
  __shared__ __align__(16) u16 Bs1[256 * 32];
  const int tid  = threadIdx.x;
  const int lane = tid & 63;
  const int wave = tid >> 6;          // 0..7
  const int wm = (wave & 1) * 64;
  const int wn = (wave >> 1) * 64;
  const int bid = blockIdx.x;
  // two-level bx-slow decode (bijective: grid = nbx*64)
  const int xcd = bid & 7;
  const int L   = bid >> 3;           // 0 .. nbx*8-1
  const int bx  = L >> 3;             // 0 .. nbx-1 (B-panel, SLOW)
  const int by  = xcd * 8 + (L & 7);  // 0 .. 63 (FAST within XCD stripe)
  const size_t bm = (size_t)by * 128;
  const u16* Ab = A + bm * (size_t)K;
  const u16* Bb = Bt + (size_t)bx * 256 * K;

  const int srow = tid >> 2;                                  // 0..127
  const int scol = (((tid & 3) ^ ((srow >> 1) & 3)) << 3);    // element col

  f32x4 acc[4][4];
#pragma unroll
  for (int i = 0; i < 4; i++)
#pragma unroll
    for (int j = 0; j < 4; j++) acc[i][j] = (f32x4){0.f, 0.f, 0.f, 0.f};

#define STAGE(AS, BS, kk)                                                \
  do {                                                                   \
    gload16(Ab + (size_t)srow * K + (kk) + scol, &AS[tid * 8]);          \
    gload16(Bb + (size_t)srow * K + (kk) + scol, &BS[tid * 8]);          \
    gload16(Bb + (size_t)(128 + srow) * K + (kk) + scol, &BS[4096 + tid * 8]); \
  } while (0)

#define COMPUTE(AS, BS)                                                           \
  do {                                                                            \
    const int fr = lane & 15;                                                     \
    const int fo = (((lane >> 4) ^ ((fr >> 1) & 3)) << 3);  /* swizzled k-off */  \
    f16x8 av[4], bv[4];                                                           \
    _Pragma("unroll")                                                             \
    for (int i = 0; i < 4; i++) av[i] = *(const f16x8*)&AS[(wm + i * 16 + fr) * 32 + fo]; \
    _Pragma("unroll")                                                             \
    for (int j = 0; j < 4; j++) bv[j] = *(const f16x8*)&BS[(wn + j * 16 + fr) * 32 + fo]; \
    __builtin_amdgcn_s_setprio(1);                                                \
    _Pragma("unroll")                                                             \
    for (int i = 0; i < 4; i++)                                                   \
      _Pragma("unroll")                                                           \
      for (int j = 0; j < 4; j++)                                                 \
        acc[i][j] = __builtin_amdgcn_mfma_f32_16x16x32_f16(av[i], bv[j], acc[i][j], 0, 0, 0); \
    __builtin_amdgcn_s_setprio(0);                                                \
  } while (0)

  STAGE(As0, Bs0, 0);            // 3 in flight
  STAGE(As1, Bs1, 32);           // 6 in flight
  WAITV3();                      // buf0's 3 landed (own wave)
  BAR();                         // => all waves' buf0 loads landed
  for (int k0 = 0; k0 < K; k0 += 64) {
    COMPUTE(As0, Bs0);
    BAR();                       // all waves done reading buf0
    if (k0 + 64 < K) { STAGE(As0, Bs0, k0 + 64); WAITV3(); }
    else             { WAITV0(); }
    BAR();                       // buf1 ready
    COMPUTE(As1, Bs1);
    BAR();                       // all waves done reading buf1
    if (k0 + 96 < K) { STAGE(As1, Bs1, k0 + 96); WAITV3(); }
    BAR();                       // buf0 (next) ready
  }
#undef STAGE
#undef COMPUTE

  // C/D layout: col = lane&15, row = (lane>>4)*4 + reg   [verified m89/m91]
  const int cr = (lane >> 4) * 4, ccol = lane & 15;
  if (MODE == 0) {
    if (bx < 16) {
      const size_t cb = (size_t)bx * 256;
#pragma unroll
      for (int i2 = 0; i2 < 4; i2++)
#pragma unroll
        for (int j = 0; j < 4; j++)
#pragma unroll
          for (int r = 0; r < 4; r++)
            Cxh[(bm + wm + i2 * 16 + cr + r) * (size_t)DGATE + cb + wn + j * 16 + ccol] =
                f2h(acc[i2][j][r]);
    } else if (bx == 16) {
      if (wn == 0) {   // only cols 0..63 are real (B 0..31, C 32..63)
#pragma unroll
        for (int i2 = 0; i2 < 4; i2++)
#pragma unroll
          for (int j = 0; j < 4; j++)
#pragma unroll
            for (int r = 0; r < 4; r++)
              Cbc[(bm + wm + i2 * 16 + cr + r) * (size_t)64 + j * 16 + ccol] =
                  acc[i2][j][r];
      }
    } else {
      const size_t cb = (size_t)(bx - 17) * 256;
#pragma unroll
      for (int i2 = 0; i2 < 4; i2++)
#pragma unroll
        for (int j = 0; j < 4; j++)
#pragma unroll
          for (int r = 0; r < 4; r++)
            Czh[(bm + wm + i2 * 16 + cr + r) * (size_t)DGATE + cb + wn + j * 16 + ccol] =
                f2h(acc[i2][j][r]);
    }
  } else {
    const size_t cb = (size_t)bx * 256;
#pragma unroll
    for (int i2 = 0; i2 < 4; i2++)
#pragma unroll
      for (int j = 0; j < 4; j++)
#pragma unroll
        for (int r = 0; r < 4; r++)
          Cf32[(bm + wm + i2 * 16 + cr + r) * (size_t)H_DIM + cb + wn + j * 16 + ccol] =
              acc[i2][j][r];
  }
}

// ---------------- chunked SSM scan (r14 exact: lane owns adjacent chans 2l,2l+1) --
// xh/zh: [M][4096] f16. xbc: [M][64] f32 (B cols 0..31, C cols 32..63).
__global__ __launch_bounds__(64)
void scan_pass1(const u16* __restrict__ xh, const float* __restrict__ xbc,
                const float* __restrict__ conv_w,
                const float* __restrict__ A_log, const float* __restrict__ dt_bias,
                float* __restrict__ E) {
  const int bid = blockIdx.x;
  const int c   = bid & (NCHUNK - 1);
  const int bg  = bid >> 6;
  const int g   = bg & (GHEADS - 1);
  const int b   = bg >> 5;
  const int lane = threadIdx.x;
  const int c0 = g * DH + 2 * lane;    // channels c0, c0+1 (adjacent)

  const f32x4 w0 = ((const f32x4*)conv_w)[c0];
  const f32x4 w1 = ((const f32x4*)conv_w)[c0 + 1];
  const float dt = log1pf(expf(dt_bias[g]));
  const float Ac = -expf(A_log[g]);
  const float dA = expf(dt * Ac);

  const int l0 = c * SCHUNK;
  const u16*   basex = xh  + (size_t)b * LSEQ * DGATE;
  const float* baseb = xbc + (size_t)b * LSEQ * 64;

  float xm3 = 0, xm2 = 0, xm1 = 0, Xm3 = 0, Xm2 = 0, Xm1 = 0;
#pragma unroll
  for (int j = 0; j < 3; j++) {
    int l = l0 - 3 + j;
    float v0 = 0, v1 = 0;
    if (l >= 0) {
      u32 v = *(const u32*)&basex[(size_t)l * DGATE + c0];
      v0 = h2f((u16)v); v1 = h2f((u16)(v >> 16));
    }
    if (j == 0) { xm3 = v0; Xm3 = v1; }
    else if (j == 1) { xm2 = v0; Xm2 = v1; }
    else { xm1 = v0; Xm1 = v1; }
  }
  float h0 = 0.f, h1 = 0.f;
  for (int t = 0; t < SCHUNK; t++) {
    const int l = l0 + t;
    u32 v = *(const u32*)&basex[(size_t)l * DGATE + c0];
    float xc0 = h2f((u16)v), xc1 = h2f((u16)(v >> 16));
    float cx0 = w0[0] * xm3 + w0[1] * xm2 + w0[2] * xm1 + w0[3] * xc0;
    float cx1 = w1[0] * Xm3 + w1[1] * Xm2 + w1[2] * Xm1 + w1[3] * xc1;
    xm3 = xm2; xm2 = xm1; xm1 = xc0;
    Xm3 = Xm2; Xm2 = Xm1; Xm1 = xc1;
    float u = dt * baseb[(size_t)l * 64 + g];
    h0 = dA * h0 + u * silu(cx0);
    h1 = dA * h1 + u * silu(cx1);
  }
  ((float2*)(E + (size_t)bid * DH))[lane] = make_float2(h0, h1);
}

__global__ __launch_bounds__(64)
void scan_pass2(const float* __restrict__ E, float* __restrict__ Hs,
                const float* __restrict__ A_log, const float* __restrict__ dt_bias) {
  const int bg = blockIdx.x;
  const int g = bg & (GHEADS - 1);
  const int lane = threadIdx.x;
  const float dt = log1pf(expf(dt_bias[g]));
  const float Ac = -expf(A_log[g]);
  const float dAS = expf(dt * Ac * (float)SCHUNK);
  float h0 = 0.f, h1 = 0.f;
  for (int c = 0; c < NCHUNK; c++) {
    size_t idx = ((size_t)bg * NCHUNK + c) * DH;
    Hs[idx + lane] = h0; Hs[idx + lane + 64] = h1;
    h0 = dAS * h0 + E[idx + lane];
    h1 = dAS * h1 + E[idx + lane + 64];
  }
}

__global__ __launch_bounds__(64)
void scan_pass3(const u16* __restrict__ xh, const u16* __restrict__ zh,
                const float* __restrict__ xbc, const float* __restrict__ conv_w,
                const float* __restrict__ A_log, const float* __restrict__ dt_bias,
                const float* __restrict__ norm_w, const float* __restrict__ Hs,
                u16* __restrict__ gbuf) {
  const int bid = blockIdx.x;
  const int c   = bid & (NCHUNK - 1);
  const int bg  = bid >> 6;
  const int g   = bg & (GHEADS - 1);
  const int b   = bg >> 5;
  const int lane = threadIdx.x;
  const int c0 = g * DH + 2 * lane;    // channels c0, c0+1 (adjacent)

  const f32x4 wx0 = ((const f32x4*)conv_w)[c0];
  const f32x4 wx1 = ((const f32x4*)conv_w)[c0 + 1];
  const f32x4 wz0 = ((const f32x4*)conv_w)[DGATE + c0];
  const f32x4 wz1 = ((const f32x4*)conv_w)[DGATE + c0 + 1];
  const float nw0 = norm_w[2 * lane], nw1 = norm_w[2 * lane + 1];

  const float dt = log1pf(expf(dt_bias[g]));
  const float Ac = -expf(A_log[g]);
  const float dA = expf(dt * Ac);

  const int l0 = c * SCHUNK;
  const u16*   basex = xh  + (size_t)b * LSEQ * DGATE;
  const u16*   basez = zh  + (size_t)b * LSEQ * DGATE;
  const float* baseb = xbc + (size_t)b * LSEQ * 64;

  float xm3 = 0, xm2 = 0, xm1 = 0, Xm3 = 0, Xm2 = 0, Xm1 = 0;
  float zm3 = 0, zm2 = 0, zm1 = 0, Zm3 = 0, Zm2 = 0, Zm1 = 0;
#pragma unroll
  for (int j = 0; j < 3; j++) {
    int l = l0 - 3 + j;
    float vx0 = 0, vx1 = 0, vz0 = 0, vz1 = 0;
    if (l >= 0) {
      u32 vx = *(const u32*)&basex[(size_t)l * DGATE + c0];
      u32 vz = *(const u32*)&basez[(size_t)l * DGATE + c0];
      vx0 = h2f((u16)vx); vx1 = h2f((u16)(vx >> 16));
      vz0 = h2f((u16)vz); vz1 = h2f((u16)(vz >> 16));
    }
    if (j == 0) { xm3 = vx0; Xm3 = vx1; zm3 = vz0; Zm3 = vz1; }
    else if (j == 1) { xm2 = vx0; Xm2 = vx1; zm2 = vz0; Zm2 = vz1; }
    else { xm1 = vx0; Xm1 = vx1; zm1 = vz0; Zm1 = vz1; }
  }
  float2 hini = ((const float2*)(Hs + (size_t)bid * DH))[lane];
  float h0 = hini.x, h1 = hini.y;
  for (int t = 0; t < SCHUNK; t++) {
    const int l = l0 + t;
    u32 vx = *(const u32*)&basex[(size_t)l * DGATE + c0];
    u32 vz = *(const u32*)&basez[(size_t)l * DGATE + c0];
    float xc0 = h2f((u16)vx), xc1 = h2f((u16)(vx >> 16));
    float zc0 = h2f((u16)vz), zc1 = h2f((u16)(vz >> 16));
    float cx0 = wx0[0] * xm3 + wx0[1] * xm2 + wx0[2] * xm1 + wx0[3] * xc0;
    float cx1 = wx1[0] * Xm3 + wx1[1] * Xm2 + wx1[2] * Xm1 + wx1[3] * xc1;
    float cz0 = wz0[0] * zm3 + wz0[1] * zm2 + wz0[2] * zm1 + wz0[3] * zc0;
    float cz1 = wz1[0] * Zm3 + wz1[1] * Zm2 + wz1[2] * Zm1 + wz1[3] * zc1;
    xm3 = xm2; xm2 = xm1; xm1 = xc0;  Xm3 = Xm2; Xm2 = Xm1; Xm1 = xc1;
    zm3 = zm2; zm2 = zm1; zm1 = zc0;  Zm3 = Zm2; Zm2 = Zm1; Zm1 = zc1;
    float bcl = baseb[(size_t)l * 64 + g];
    float ccl = baseb[(size_t)l * 64 + 32 + g];
    float u = dt * bcl;
    h0 = dA * h0 + u * silu(cx0);
    h1 = dA * h1 + u * silu(cx1);
    float y0 = ccl * h0, y1 = ccl * h1;
    float ss = y0 * y0 + y1 * y1;
    ss += __shfl_xor(ss, 32); ss += __shfl_xor(ss, 16); ss += __shfl_xor(ss, 8);
    ss += __shfl_xor(ss, 4);  ss += __shfl_xor(ss, 2);  ss += __shfl_xor(ss, 1);
    const float sc = rsqrtf(ss * (1.0f / DH) + 1e-6f);
    u32 o = (u32)f2h(y0 * sc * nw0 * silu(cz0)) |
            ((u32)f2h(y1 * sc * nw1 * silu(cz1)) << 16);
    *(u32*)&gbuf[(size_t)(b * LSEQ + l) * DGATE + c0] = o;
  }
}

// ---------------- launch ----------------
extern "C" void kernel_launch(void* const* d_in, const int* in_sizes, int n_in,
                              void* d_out, int out_size, void* d_ws, size_t ws_size,
                              hipStream_t stream) {
  (void)in_sizes; (void)n_in; (void)out_size; (void)ws_size;
  const float* hs    = (const float*)d_in[0];
  const float* Wqkv  = (const float*)d_in[1];
  const float* Wb    = (const float*)d_in[2];
  const float* Wa    = (const float*)d_in[3];
  const float* convw = (const float*)d_in[4];
  const float* Wout  = (const float*)d_in[5];
  const float* normw = (const float*)d_in[6];
  const float* Alog  = (const float*)d_in[7];
  const float* dtb   = (const float*)d_in[8];
  float* out = (float*)d_out;

  // ws layout (~230 MB; <= 313 proven-safe):
  // [xh 67.1 | zh 67.1 | xbc 2.1 | wcomb 43.3 | pad 25 | wout 21.0 | E 2.1 | Hst 2.1]
  char* ws = (char*)d_ws;
  size_t off = 0;
  auto alloc = [&](size_t bytes) { void* p = ws + off; off += (bytes + 255) & ~(size_t)255; return p; };
  u16*   xh     = (u16*)alloc((size_t)MROWS * DGATE * 2);        // 67.1 MB
  u16*   zh     = (u16*)alloc((size_t)MROWS * DGATE * 2);        // 67.1 MB
  float* xbc    = (float*)alloc((size_t)MROWS * 64 * 4);         // 2.1 MB
  u16*   wcomb  = (u16*)alloc((size_t)NWCOMB * H_DIM * 2);       // 43.3 MB
  (void)alloc((size_t)25 << 20);                                 // 25 MB pad (gbuf tail)
  u16*   wout_h = (u16*)alloc((size_t)H_DIM * DGATE * 2);        // 21.0 MB
  float* E      = (float*)alloc((size_t)BSZ * GHEADS * NCHUNK * DH * 4);
  float* Hst    = (float*)alloc((size_t)BSZ * GHEADS * NCHUNK * DH * 4);
  // gbuf (67.1 MB) aliases [wcomb|pad] (68.3 MB): wcomb is dead after GEMM1;
  // pass3 (writer) launches strictly after it. Never touches wout.
  u16*   gbuf   = wcomb;
  // hs_h (fp16, 41.9 MB) lives in d_out (83.9 MB), dead until GEMM2 overwrites it.
  u16*   hs_h   = (u16*)d_out;

  // merged prep: hs cast + wout cast + wcomb build. 13,271,040 granules / 256.
  prep_all<<<51840, 256, 0, stream>>>(hs, Wqkv, Wb, Wa, Wout, hs_h, wout_h, wcomb);

  // Fused GEMM1: [x -> f16 xh] + [B/C -> f32 xbc] + [z -> f16 zh].
  // grid 33 bx * 64 by = 2112
  gemm_h<0><<<2112, 512, 0, stream>>>(hs_h, wcomb, xh, xbc, zh, nullptr,
                                      H_DIM, 33);

  scan_pass1<<<BSZ * GHEADS * NCHUNK, 64, 0, stream>>>(xh, xbc, convw, Alog, dtb, E);
  scan_pass2<<<BSZ * GHEADS, 64, 0, stream>>>(E, Hst, Alog, dtb);
  scan_pass3<<<BSZ * GHEADS * NCHUNK, 64, 0, stream>>>(xh, zh, xbc, convw, Alog, dtb,
                                                       normw, Hst, gbuf);

  // GEMM2: out = gated @ W_out^T -> f32 [8192, 2560].  grid 10*64 = 640
  gemm_h<1><<<640, 512, 0, stream>>>(gbuf, wout_h, nullptr, nullptr, nullptr,
                                     out, DGATE, 10);
}

// Round 17
// 766.859 us; speedup vs baseline: 1.1378x; 1.0237x over previous
//
#include <hip/hip_runtime.h>
#include <cstdint>
#include <cstddef>

// ---------------- problem geometry ----------------
#define H_DIM   2560
#define DINNER  8192
#define GHEADS  32
#define DGATE   4096
#define DH      128
#define BSZ     2
#define LSEQ    4096
#define MROWS   (BSZ*LSEQ)     // 8192 token rows
#define NWCOMB  8448           // wcomb rows: x 4096 | B 32 | C 32 | pad 192 | z 4096 (=33*256)
#define NCHUNK  128            // r17: 64 -> 128 (halve scan serial chain, fill wave capacity)
#define SCHUNK  (LSEQ/NCHUNK)  // 32

typedef __attribute__((ext_vector_type(4))) float    f32x4;
typedef __attribute__((ext_vector_type(8))) _Float16 f16x8;
typedef unsigned short u16;
typedef unsigned int   u32;

static __device__ __forceinline__ u16 f2h(float f) {
  _Float16 h = (_Float16)f;          // v_cvt_f16_f32, RNE
  union { _Float16 h; u16 u; } v; v.h = h; return v.u;
}
static __device__ __forceinline__ float h2f(u16 u) {
  union { u16 u; _Float16 h; } v; v.u = u; return (float)v.h;
}
static __device__ __forceinline__ float silu(float x) {
  return x / (1.0f + expf(-x));
}

// ---------------- merged prep: hs cast | wout cast | wcomb build ----------------
__global__ __launch_bounds__(256)
void prep_all(const float* __restrict__ hs, const float* __restrict__ Wqkv,
              const float* __restrict__ Wb, const float* __restrict__ Wa,
              const float* __restrict__ Wout, u16* __restrict__ hs_h,
              u16* __restrict__ wout_h, u16* __restrict__ wcomb) {
  const size_t G1 = (size_t)MROWS * H_DIM / 4;
  const size_t G2 = (size_t)DGATE * H_DIM / 4;
  size_t gid = (size_t)blockIdx.x * 256 + threadIdx.x;
  if (gid < G1) {
    f32x4 v = ((const f32x4*)hs)[gid];
    ((uint2*)hs_h)[gid] = make_uint2((u32)f2h(v[0]) | ((u32)f2h(v[1]) << 16),
                                     (u32)f2h(v[2]) | ((u32)f2h(v[3]) << 16));
  } else if (gid < G1 + G2) {
    size_t i = gid - G1;
    f32x4 v = ((const f32x4*)Wout)[i];
    ((uint2*)wout_h)[i] = make_uint2((u32)f2h(v[0]) | ((u32)f2h(v[1]) << 16),
                                     (u32)f2h(v[2]) | ((u32)f2h(v[3]) << 16));
  } else {
    size_t i = gid - G1 - G2;          // 0 .. 8448*640-1
    int row = (int)(i / 640);
    int col = (int)(i - (size_t)row * 640);
    const float* s = nullptr;
    if (row < 4096)              s = Wqkv + (size_t)row * H_DIM;
    else if (row < 4128)         s = Wb + (size_t)(row - 4096) * H_DIM;
    else if (row < 4160)         s = Wa + (size_t)(row - 4128) * H_DIM;
    else if (row >= 4352)        s = Wqkv + (size_t)(4096 + row - 4352) * H_DIM;
    u32 p0 = 0, p1 = 0;
    if (s) {
      f32x4 v = ((const f32x4*)s)[col];
      p0 = (u32)f2h(v[0]) | ((u32)f2h(v[1]) << 16);
      p1 = (u32)f2h(v[2]) | ((u32)f2h(v[3]) << 16);
    }
    ((uint2*)(wcomb + (size_t)row * H_DIM))[col] = make_uint2(p0, p1);
  }
}

// ---------------- GEMM (r16 exact: proven 785-us config, DO NOT TOUCH) -------
static __device__ __forceinline__ void gload16(const u16* g, u16* l) {
  __builtin_amdgcn_global_load_lds(
      (const __attribute__((address_space(1))) u32*)g,
      (__attribute__((address_space(3))) u32*)l, 16, 0, 0);
}

#define BAR()    asm volatile("s_barrier" ::: "memory")
#define WAITV3() asm volatile("s_waitcnt vmcnt(3)" ::: "memory")
#define WAITV0() asm volatile("s_waitcnt vmcnt(0)" ::: "memory")

// C[m,n] = sum_k A[m,k]*Bt[n,k], fp16 in. 128M x 256N tile, 512 thr (8 waves
// 2x4, per-wave 64x64, 4x4 16x16x32 frags). Double-buffered LDS with COUNTED
// vmcnt(3); T2 slot-swizzle (conflict-0); T5 setprio; 48 KB LDS -> 3 blocks/CU.
// TWO-LEVEL bx-slow XCD decode (r16-verified: FETCH 1.39->0.39 GB, util 34->41.5%):
// xcd=bid&7 owns by-stripe; by fast, bx slow -> B-panel L2-stationary.
// MODE 0 (fused GEMM1): bx<16 -> f16 Cxh col bx*256; bx==16 -> f32 Cbc[M][64]
// (wn==0 waves only); bx>16 -> f16 Czh col (bx-17)*256.
// MODE 1 (GEMM2): f32 Cf32, ldc 2560, col bx*256.
template<int MODE>
__global__ __launch_bounds__(512)
void gemm_h(const u16* __restrict__ A, const u16* __restrict__ Bt,
            u16* __restrict__ Cxh, float* __restrict__ Cbc, u16* __restrict__ Czh,
            float* __restrict__ Cf32, int K, int nbx) {
  __shared__ __align__(16) u16 As0[128 * 32];
  __shared__ __align__(16) u16 As1[128 * 32];
  __shared__ __align__(16) u16 Bs0[256 * 32];
  __shared__ __align__(16) u16 Bs1[256 * 32];
  const int tid  = threadIdx.x;
  const int lane = tid & 63;
  const int wave = tid >> 6;          // 0..7
  const int wm = (wave & 1) * 64;
  const int wn = (wave >> 1) * 64;
  const int bid = blockIdx.x;
  const int xcd = bid & 7;
  const int L   = bid >> 3;           // 0 .. nbx*8-1
  const int bx  = L >> 3;             // 0 .. nbx-1 (B-panel, SLOW)
  const int by  = xcd * 8 + (L & 7);  // 0 .. 63 (FAST within XCD stripe)
  const size_t bm = (size_t)by * 128;
  const u16* Ab = A + bm * (size_t)K;
  const u16* Bb = Bt + (size_t)bx * 256 * K;

  const int srow = tid >> 2;                                  // 0..127
  const int scol = (((tid & 3) ^ ((srow >> 1) & 3)) << 3);    // element col

  f32x4 acc[4][4];
#pragma unroll
  for (int i = 0; i < 4; i++)
#pragma unroll
    for (int j = 0; j < 4; j++) acc[i][j] = (f32x4){0.f, 0.f, 0.f, 0.f};

#define STAGE(AS, BS, kk)                                                \
  do {                                                                   \
    gload16(Ab + (size_t)srow * K + (kk) + scol, &AS[tid * 8]);          \
    gload16(Bb + (size_t)srow * K + (kk) + scol, &BS[tid * 8]);          \
    gload16(Bb + (size_t)(128 + srow) * K + (kk) + scol, &BS[4096 + tid * 8]); \
  } while (0)

#define COMPUTE(AS, BS)                                                           \
  do {                                                                            \
    const int fr = lane & 15;                                                     \
    const int fo = (((lane >> 4) ^ ((fr >> 1) & 3)) << 3);  /* swizzled k-off */  \
    f16x8 av[4], bv[4];                                                           \
    _Pragma("unroll")                                                             \
    for (int i = 0; i < 4; i++) av[i] = *(const f16x8*)&AS[(wm + i * 16 + fr) * 32 + fo]; \
    _Pragma("unroll")                                                             \
    for (int j = 0; j < 4; j++) bv[j] = *(const f16x8*)&BS[(wn + j * 16 + fr) * 32 + fo]; \
    __builtin_amdgcn_s_setprio(1);                                                \
    _Pragma("unroll")                                                             \
    for (int i = 0; i < 4; i++)                                                   \
      _Pragma("unroll")                                                           \
      for (int j = 0; j < 4; j++)                                                 \
        acc[i][j] = __builtin_amdgcn_mfma_f32_16x16x32_f16(av[i], bv[j], acc[i][j], 0, 0, 0); \
    __builtin_amdgcn_s_setprio(0);                                                \
  } while (0)

  STAGE(As0, Bs0, 0);            // 3 in flight
  STAGE(As1, Bs1, 32);           // 6 in flight
  WAITV3();                      // buf0's 3 landed (own wave)
  BAR();                         // => all waves' buf0 loads landed
  for (int k0 = 0; k0 < K; k0 += 64) {
    COMPUTE(As0, Bs0);
    BAR();                       // all waves done reading buf0
    if (k0 + 64 < K) { STAGE(As0, Bs0, k0 + 64); WAITV3(); }
    else             { WAITV0(); }
    BAR();                       // buf1 ready
    COMPUTE(As1, Bs1);
    BAR();                       // all waves done reading buf1
    if (k0 + 96 < K) { STAGE(As1, Bs1, k0 + 96); WAITV3(); }
    BAR();                       // buf0 (next) ready
  }
#undef STAGE
#undef COMPUTE

  // C/D layout: col = lane&15, row = (lane>>4)*4 + reg   [verified m89/m91]
  const int cr = (lane >> 4) * 4, ccol = lane & 15;
  if (MODE == 0) {
    if (bx < 16) {
      const size_t cb = (size_t)bx * 256;
#pragma unroll
      for (int i2 = 0; i2 < 4; i2++)
#pragma unroll
        for (int j = 0; j < 4; j++)
#pragma unroll
          for (int r = 0; r < 4; r++)
            Cxh[(bm + wm + i2 * 16 + cr + r) * (size_t)DGATE + cb + wn + j * 16 + ccol] =
                f2h(acc[i2][j][r]);
    } else if (bx == 16) {
      if (wn == 0) {   // only cols 0..63 are real (B 0..31, C 32..63)
#pragma unroll
        for (int i2 = 0; i2 < 4; i2++)
#pragma unroll
          for (int j = 0; j < 4; j++)
#pragma unroll
            for (int r = 0; r < 4; r++)
              Cbc[(bm + wm + i2 * 16 + cr + r) * (size_t)64 + j * 16 + ccol] =
                  acc[i2][j][r];
      }
    } else {
      const size_t cb = (size_t)(bx - 17) * 256;
#pragma unroll
      for (int i2 = 0; i2 < 4; i2++)
#pragma unroll
        for (int j = 0; j < 4; j++)
#pragma unroll
          for (int r = 0; r < 4; r++)
            Czh[(bm + wm + i2 * 16 + cr + r) * (size_t)DGATE + cb + wn + j * 16 + ccol] =
                f2h(acc[i2][j][r]);
    }
  } else {
    const size_t cb = (size_t)bx * 256;
#pragma unroll
    for (int i2 = 0; i2 < 4; i2++)
#pragma unroll
      for (int j = 0; j < 4; j++)
#pragma unroll
        for (int r = 0; r < 4; r++)
          Cf32[(bm + wm + i2 * 16 + cr + r) * (size_t)H_DIM + cb + wn + j * 16 + ccol] =
              acc[i2][j][r];
  }
}

// ---------------- chunked SSM scan (NCHUNK=128; lane owns adjacent chans 2l,2l+1) --
// xh/zh: [M][4096] f16. xbc: [M][64] f32 (B cols 0..31, C cols 32..63).
__global__ __launch_bounds__(64)
void scan_pass1(const u16* __restrict__ xh, const float* __restrict__ xbc,
                const float* __restrict__ conv_w,
                const float* __restrict__ A_log, const float* __restrict__ dt_bias,
                float* __restrict__ E) {
  const int bid = blockIdx.x;
  const int c   = bid & (NCHUNK - 1);
  const int bg  = bid >> 7;            // NCHUNK=128 -> shift 7
  const int g   = bg & (GHEADS - 1);
  const int b   = bg >> 5;
  const int lane = threadIdx.x;
  const int c0 = g * DH + 2 * lane;    // channels c0, c0+1 (adjacent)

  const f32x4 w0 = ((const f32x4*)conv_w)[c0];
  const f32x4 w1 = ((const f32x4*)conv_w)[c0 + 1];
  const float dt = log1pf(expf(dt_bias[g]));
  const float Ac = -expf(A_log[g]);
  const float dA = expf(dt * Ac);

  const int l0 = c * SCHUNK;
  const u16*   basex = xh  + (size_t)b * LSEQ * DGATE;
  const float* baseb = xbc + (size_t)b * LSEQ * 64;

  float xm3 = 0, xm2 = 0, xm1 = 0, Xm3 = 0, Xm2 = 0, Xm1 = 0;
#pragma unroll
  for (int j = 0; j < 3; j++) {
    int l = l0 - 3 + j;
    float v0 = 0, v1 = 0;
    if (l >= 0) {
      u32 v = *(const u32*)&basex[(size_t)l * DGATE + c0];
      v0 = h2f((u16)v); v1 = h2f((u16)(v >> 16));
    }
    if (j == 0) { xm3 = v0; Xm3 = v1; }
    else if (j == 1) { xm2 = v0; Xm2 = v1; }
    else { xm1 = v0; Xm1 = v1; }
  }
  float h0 = 0.f, h1 = 0.f;
  for (int t = 0; t < SCHUNK; t++) {
    const int l = l0 + t;
    u32 v = *(const u32*)&basex[(size_t)l * DGATE + c0];
    float xc0 = h2f((u16)v), xc1 = h2f((u16)(v >> 16));
    float cx0 = w0[0] * xm3 + w0[1] * xm2 + w0[2] * xm1 + w0[3] * xc0;
    float cx1 = w1[0] * Xm3 + w1[1] * Xm2 + w1[2] * Xm1 + w1[3] * xc1;
    xm3 = xm2; xm2 = xm1; xm1 = xc0;
    Xm3 = Xm2; Xm2 = Xm1; Xm1 = xc1;
    float u = dt * baseb[(size_t)l * 64 + g];
    h0 = dA * h0 + u * silu(cx0);
    h1 = dA * h1 + u * silu(cx1);
  }
  ((float2*)(E + (size_t)bid * DH))[lane] = make_float2(h0, h1);
}

__global__ __launch_bounds__(64)
void scan_pass2(const float* __restrict__ E, float* __restrict__ Hs,
                const float* __restrict__ A_log, const float* __restrict__ dt_bias) {
  const int bg = blockIdx.x;
  const int g = bg & (GHEADS - 1);
  const int lane = threadIdx.x;
  const float dt = log1pf(expf(dt_bias[g]));
  const float Ac = -expf(A_log[g]);
  const float dAS = expf(dt * Ac * (float)SCHUNK);
  float h0 = 0.f, h1 = 0.f;
  for (int c = 0; c < NCHUNK; c++) {
    size_t idx = ((size_t)bg * NCHUNK + c) * DH;
    Hs[idx + lane] = h0; Hs[idx + lane + 64] = h1;
    h0 = dAS * h0 + E[idx + lane];
    h1 = dAS * h1 + E[idx + lane + 64];
  }
}

__global__ __launch_bounds__(64)
void scan_pass3(const u16* __restrict__ xh, const u16* __restrict__ zh,
                const float* __restrict__ xbc, const float* __restrict__ conv_w,
                const float* __restrict__ A_log, const float* __restrict__ dt_bias,
                const float* __restrict__ norm_w, const float* __restrict__ Hs,
                u16* __restrict__ gbuf) {
  const int bid = blockIdx.x;
  const int c   = bid & (NCHUNK - 1);
  const int bg  = bid >> 7;            // NCHUNK=128 -> shift 7
  const int g   = bg & (GHEADS - 1);
  const int b   = bg >> 5;
  const int lane = threadIdx.x;
  const int c0 = g * DH + 2 * lane;    // channels c0, c0+1 (adjacent)

  const f32x4 wx0 = ((const f32x4*)conv_w)[c0];
  const f32x4 wx1 = ((const f32x4*)conv_w)[c0 + 1];
  const f32x4 wz0 = ((const f32x4*)conv_w)[DGATE + c0];
  const f32x4 wz1 = ((const f32x4*)conv_w)[DGATE + c0 + 1];
  const float nw0 = norm_w[2 * lane], nw1 = norm_w[2 * lane + 1];

  const float dt = log1pf(expf(dt_bias[g]));
  const float Ac = -expf(A_log[g]);
  const float dA = expf(dt * Ac);

  const int l0 = c * SCHUNK;
  const u16*   basex = xh  + (size_t)b * LSEQ * DGATE;
  const u16*   basez = zh  + (size_t)b * LSEQ * DGATE;
  const float* baseb = xbc + (size_t)b * LSEQ * 64;

  float xm3 = 0, xm2 = 0, xm1 = 0, Xm3 = 0, Xm2 = 0, Xm1 = 0;
  float zm3 = 0, zm2 = 0, zm1 = 0, Zm3 = 0, Zm2 = 0, Zm1 = 0;
#pragma unroll
  for (int j = 0; j < 3; j++) {
    int l = l0 - 3 + j;
    float vx0 = 0, vx1 = 0, vz0 = 0, vz1 = 0;
    if (l >= 0) {
      u32 vx = *(const u32*)&basex[(size_t)l * DGATE + c0];
      u32 vz = *(const u32*)&basez[(size_t)l * DGATE + c0];
      vx0 = h2f((u16)vx); vx1 = h2f((u16)(vx >> 16));
      vz0 = h2f((u16)vz); vz1 = h2f((u16)(vz >> 16));
    }
    if (j == 0) { xm3 = vx0; Xm3 = vx1; zm3 = vz0; Zm3 = vz1; }
    else if (j == 1) { xm2 = vx0; Xm2 = vx1; zm2 = vz0; Zm2 = vz1; }
    else { xm1 = vx0; Xm1 = vx1; zm1 = vz0; Zm1 = vz1; }
  }
  float2 hini = ((const float2*)(Hs + (size_t)bid * DH))[lane];
  float h0 = hini.x, h1 = hini.y;
  for (int t = 0; t < SCHUNK; t++) {
    const int l = l0 + t;
    u32 vx = *(const u32*)&basex[(size_t)l * DGATE + c0];
    u32 vz = *(const u32*)&basez[(size_t)l * DGATE + c0];
    float xc0 = h2f((u16)vx), xc1 = h2f((u16)(vx >> 16));
    float zc0 = h2f((u16)vz), zc1 = h2f((u16)(vz >> 16));
    float cx0 = wx0[0] * xm3 + wx0[1] * xm2 + wx0[2] * xm1 + wx0[3] * xc0;
    float cx1 = wx1[0] * Xm3 + wx1[1] * Xm2 + wx1[2] * Xm1 + wx1[3] * xc1;
    float cz0 = wz0[0] * zm3 + wz0[1] * zm2 + wz0[2] * zm1 + wz0[3] * zc0;
    float cz1 = wz1[0] * Zm3 + wz1[1] * Zm2 + wz1[2] * Zm1 + wz1[3] * zc1;
    xm3 = xm2; xm2 = xm1; xm1 = xc0;  Xm3 = Xm2; Xm2 = Xm1; Xm1 = xc1;
    zm3 = zm2; zm2 = zm1; zm1 = zc0;  Zm3 = Zm2; Zm2 = Zm1; Zm1 = zc1;
    float bcl = baseb[(size_t)l * 64 + g];
    float ccl = baseb[(size_t)l * 64 + 32 + g];
    float u = dt * bcl;
    h0 = dA * h0 + u * silu(cx0);
    h1 = dA * h1 + u * silu(cx1);
    float y0 = ccl * h0, y1 = ccl * h1;
    float ss = y0 * y0 + y1 * y1;
    ss += __shfl_xor(ss, 32); ss += __shfl_xor(ss, 16); ss += __shfl_xor(ss, 8);
    ss += __shfl_xor(ss, 4);  ss += __shfl_xor(ss, 2);  ss += __shfl_xor(ss, 1);
    const float sc = rsqrtf(ss * (1.0f / DH) + 1e-6f);
    u32 o = (u32)f2h(y0 * sc * nw0 * silu(cz0)) |
            ((u32)f2h(y1 * sc * nw1 * silu(cz1)) << 16);
    *(u32*)&gbuf[(size_t)(b * LSEQ + l) * DGATE + c0] = o;
  }
}

// ---------------- launch ----------------
extern "C" void kernel_launch(void* const* d_in, const int* in_sizes, int n_in,
                              void* d_out, int out_size, void* d_ws, size_t ws_size,
                              hipStream_t stream) {
  (void)in_sizes; (void)n_in; (void)out_size; (void)ws_size;
  const float* hs    = (const float*)d_in[0];
  const float* Wqkv  = (const float*)d_in[1];
  const float* Wb    = (const float*)d_in[2];
  const float* Wa    = (const float*)d_in[3];
  const float* convw = (const float*)d_in[4];
  const float* Wout  = (const float*)d_in[5];
  const float* normw = (const float*)d_in[6];
  const float* Alog  = (const float*)d_in[7];
  const float* dtb   = (const float*)d_in[8];
  float* out = (float*)d_out;

  // ws layout (~234 MB; <= 313 proven-safe):
  // [xh 67.1 | zh 67.1 | xbc 2.1 | wcomb 43.3 | pad 25 | wout 21.0 | E 4.2 | Hst 4.2]
  char* ws = (char*)d_ws;
  size_t off = 0;
  auto alloc = [&](size_t bytes) { void* p = ws + off; off += (bytes + 255) & ~(size_t)255; return p; };
  u16*   xh     = (u16*)alloc((size_t)MROWS * DGATE * 2);        // 67.1 MB
  u16*   zh     = (u16*)alloc((size_t)MROWS * DGATE * 2);        // 67.1 MB
  float* xbc    = (float*)alloc((size_t)MROWS * 64 * 4);         // 2.1 MB
  u16*   wcomb  = (u16*)alloc((size_t)NWCOMB * H_DIM * 2);       // 43.3 MB
  (void)alloc((size_t)25 << 20);                                 // 25 MB pad (gbuf tail)
  u16*   wout_h = (u16*)alloc((size_t)H_DIM * DGATE * 2);        // 21.0 MB
  float* E      = (float*)alloc((size_t)BSZ * GHEADS * NCHUNK * DH * 4);  // 4.2 MB
  float* Hst    = (float*)alloc((size_t)BSZ * GHEADS * NCHUNK * DH * 4);  // 4.2 MB
  // gbuf (67.1 MB) aliases [wcomb|pad] (68.3 MB): wcomb is dead after GEMM1;
  // pass3 (writer) launches strictly after it. Never touches wout.
  u16*   gbuf   = wcomb;
  // hs_h (fp16, 41.9 MB) lives in d_out (83.9 MB), dead until GEMM2 overwrites it.
  u16*   hs_h   = (u16*)d_out;

  // merged prep: hs cast + wout cast + wcomb build. 13,271,040 granules / 256.
  prep_all<<<51840, 256, 0, stream>>>(hs, Wqkv, Wb, Wa, Wout, hs_h, wout_h, wcomb);

  // Fused GEMM1: [x -> f16 xh] + [B/C -> f32 xbc] + [z -> f16 zh].
  // grid 33 bx * 64 by = 2112
  gemm_h<0><<<2112, 512, 0, stream>>>(hs_h, wcomb, xh, xbc, zh, nullptr,
                                      H_DIM, 33);

  scan_pass1<<<BSZ * GHEADS * NCHUNK, 64, 0, stream>>>(xh, xbc, convw, Alog, dtb, E);
  scan_pass2<<<BSZ * GHEADS, 64, 0, stream>>>(E, Hst, Alog, dtb);
  scan_pass3<<<BSZ * GHEADS * NCHUNK, 64, 0, stream>>>(xh, zh, xbc, convw, Alog, dtb,
                                                       normw, Hst, gbuf);

  // GEMM2: out = gated @ W_out^T -> f32 [8192, 2560].  grid 10*64 = 640
  gemm_h<1><<<640, 512, 0, stream>>>(gbuf, wout_h, nullptr, nullptr, nullptr,
                                     out, DGATE, 10);
}